// Round 5
// baseline (204.575 us; speedup 1.0000x reference)
//
#include <hip/hip_runtime.h>
#include <hip/hip_cooperative_groups.h>
#include <math.h>

namespace cg = cooperative_groups;

#define NB 2
#define LSEQ 2048
#define DM 512
#define MM 64
#define CHK 64
#define NCHUNK 32

typedef __attribute__((ext_vector_type(8))) short short8v;
typedef __attribute__((ext_vector_type(4))) float f32x4;

constexpr size_t BLM   = (size_t)NB * LSEQ * MM;          // 262144
constexpr size_t BLD   = (size_t)NB * LSEQ * DM;          // 2097152
constexpr size_t BL    = (size_t)NB * LSEQ;               // 4096
constexpr size_t BNCMD = (size_t)NB * NCHUNK * MM * DM;   // 2097152
constexpr size_t BNCM  = (size_t)NB * NCHUNK * MM;        // 4096
constexpr size_t WSZ   = (size_t)DM * DM;                 // 262144

__device__ __forceinline__ float get_ld_f(const float* __restrict__ logit) {
    float lg = *logit;
    float dec = 1.0f / (1.0f + expf(-lg));
    dec = fmaxf(dec, 1e-6f);
    return logf(dec);
}
__device__ __forceinline__ float cpos(float ld, int t) {
    return fminf(fmaxf(ld * (float)t, -20.0f), 20.0f);
}
__device__ __forceinline__ float phi_fn(float v) {
    return v > 0.0f ? v + 1.0f : expf(v);
}
__device__ __forceinline__ unsigned short f2bf(float f) {
    unsigned int u = __float_as_uint(f);
    u += 0x7FFFu + ((u >> 16) & 1u);   // RNE
    return (unsigned short)(u >> 16);
}
__device__ __forceinline__ float bf2f(unsigned short h) {
    unsigned int u = ((unsigned int)h) << 16;
    return __uint_as_float(u);
}
// load 8 f32, convert to 8 bf16 packed in a uint4
__device__ __forceinline__ uint4 cvt8(const float* __restrict__ p) {
    float4 a = *(const float4*)p;
    float4 b = *(const float4*)(p + 4);
    union { unsigned short u[8]; uint4 v; } r;
    r.u[0] = f2bf(a.x); r.u[1] = f2bf(a.y); r.u[2] = f2bf(a.z); r.u[3] = f2bf(a.w);
    r.u[4] = f2bf(b.x); r.u[5] = f2bf(b.y); r.u[6] = f2bf(b.z); r.u[7] = f2bf(b.w);
    return r.v;
}

struct SmemGemm {
    unsigned short A[128][40];
    unsigned short B[128][40];
};
struct SmemLocal {
    unsigned short Qs[64][72];
    unsigned short Ks[64][72];
    unsigned short As[64][72];
    unsigned short Kws[64][66];
    unsigned short Vs[64][134];
    float wks[64], cps[64], DIsh[64];
};
struct SmemComb {
    unsigned short Qs[32][72];
    unsigned short Ssh[64][514];
    float wsh[512];
    float gv[32], invden[32], xsq[32], rinv[32];
};
union SmemAll { SmemGemm g; SmemLocal l; SmemComb c; };

__global__ __launch_bounds__(256) void mega(
    const float* __restrict__ x, const float* __restrict__ W_q,
    const float* __restrict__ W_k, const float* __restrict__ W_v,
    const float* __restrict__ W_o, const float* __restrict__ logit,
    const float* __restrict__ norm_w, float* __restrict__ out,
    float* __restrict__ wsf)
{
    __shared__ SmemAll sm;
    cg::grid_group grid = cg::this_grid();
    const int bid = blockIdx.x;
    const int tid = threadIdx.x;
    const int lane = tid & 63, wid = tid >> 6;
    const int lr = lane & 15, lk = lane >> 4;
    const float ld = get_ld_f(logit);

    // workspace layout
    float* OI = wsf;                 // BLD
    float* DI = OI + BLD;            // BL
    float* KV = DI + BL;             // BNCMD
    float* KZ = KV + BNCMD;          // BNCM
    float* ZS = KZ + BNCM;           // BNCM
    unsigned short* Qb16  = (unsigned short*)(ZS + BNCM);
    unsigned short* Kb16  = Qb16 + BLM;
    unsigned short* Vb16  = Kb16 + BLM;
    unsigned short* SSb   = Vb16 + BLD;
    unsigned short* NRMb  = SSb + BNCMD;
    unsigned short* Wob16 = NRMb + BLD;

    // ================= phase 1: QKV projection (+ W_o cvt on idle blocks) ====
    if (bid < 160) {
        const int brow = (bid & 31) * 128;
        const int cb = bid >> 5;              // 0=QK, 1..4 = V col slices
        const int wr = wid >> 1, wc = wid & 1;

        f32x4 acc[4][4];
#pragma unroll
        for (int i = 0; i < 4; ++i)
#pragma unroll
            for (int j = 0; j < 4; ++j) acc[i][j] = (f32x4)(0.f);

        for (int k0 = 0; k0 < DM; k0 += 32) {
#pragma unroll
            for (int i = 0; i < 2; ++i) {
                int c = tid * 2 + i;
                int r = c >> 2, kg = c & 3;
                *(uint4*)&sm.g.A[r][kg * 8] =
                    cvt8(&x[(size_t)(brow + r) * DM + k0 + kg * 8]);
                const float* wsrc;
                if (cb == 0)
                    wsrc = (r < 64) ? &W_q[(size_t)r * DM + k0 + kg * 8]
                                    : &W_k[(size_t)(r - 64) * DM + k0 + kg * 8];
                else
                    wsrc = &W_v[(size_t)((cb - 1) * 128 + r) * DM + k0 + kg * 8];
                *(uint4*)&sm.g.B[r][kg * 8] = cvt8(wsrc);
            }
            __syncthreads();
            short8v af[4], bf[4];
#pragma unroll
            for (int mt = 0; mt < 4; ++mt)
                af[mt] = *(const short8v*)&sm.g.A[wr * 64 + mt * 16 + lr][lk * 8];
#pragma unroll
            for (int nt = 0; nt < 4; ++nt)
                bf[nt] = *(const short8v*)&sm.g.B[wc * 64 + nt * 16 + lr][lk * 8];
#pragma unroll
            for (int mt = 0; mt < 4; ++mt)
#pragma unroll
                for (int nt = 0; nt < 4; ++nt)
                    acc[mt][nt] = __builtin_amdgcn_mfma_f32_16x16x32_bf16(
                        af[mt], bf[nt], acc[mt][nt], 0, 0, 0);
            __syncthreads();
        }
#pragma unroll
        for (int mt = 0; mt < 4; ++mt)
#pragma unroll
            for (int nt = 0; nt < 4; ++nt) {
                const int col = wc * 64 + nt * 16 + lr;
#pragma unroll
                for (int j = 0; j < 4; ++j) {
                    const int row = brow + wr * 64 + mt * 16 + lk * 4 + j;
                    float v = acc[mt][nt][j];
                    if (cb == 0) {
                        v = phi_fn(v);
                        if (col < 64)
                            Qb16[(size_t)row * MM + col] = f2bf(v * 0.125f);
                        else
                            Kb16[(size_t)row * MM + (col - 64)] = f2bf(v);
                    } else {
                        Vb16[(size_t)row * DM + (cb - 1) * 128 + col] = f2bf(v);
                    }
                }
            }
    } else {
        // idle blocks convert W_o -> bf16
        for (int i = (bid - 160) * 256 + tid; i < (int)(WSZ / 4); i += 96 * 256) {
            float4 v = ((const float4*)W_o)[i];
            ushort4 o;
            o.x = f2bf(v.x); o.y = f2bf(v.y); o.z = f2bf(v.z); o.w = f2bf(v.w);
            ((ushort4*)Wob16)[i] = o;
        }
    }
    grid.sync();

    // ================= phase 2: intra-chunk attention + summaries ============
    {
        const int chunk = bid & 31, dg = (bid >> 5) & 3, b = bid >> 7;
        const int wr = wid >> 1, wc = wid & 1;
        const int t0 = chunk * CHK;
        auto& L = sm.l;

        if (tid < 64) {
            const float c = cpos(ld, t0 + tid);
            L.cps[tid] = c;
            L.wks[tid] = expf(cpos(ld, t0 + CHK - 1) - c);
            L.DIsh[tid] = 0.f;
        }
        __syncthreads();

        const unsigned short* Qg = Qb16 + ((size_t)b * LSEQ + t0) * MM;
        const unsigned short* Kg = Kb16 + ((size_t)b * LSEQ + t0) * MM;
#pragma unroll
        for (int l = 0; l < 2; ++l) {
            const int e = tid + l * 256;
            const int r = e >> 3, gq = e & 7;
            *(uint4*)&L.Qs[r][gq * 8] = *(const uint4*)(Qg + (size_t)e * 8);
            uint4 kraw = *(const uint4*)(Kg + (size_t)e * 8);
            *(uint4*)&L.Ks[r][gq * 8] = kraw;
            const float w = L.wks[r];
            const unsigned short* kp = (const unsigned short*)&kraw;
#pragma unroll
            for (int p = 0; p < 4; ++p) {
                ushort2 o;
                o.x = f2bf(w * bf2f(kp[2 * p]));
                o.y = f2bf(w * bf2f(kp[2 * p + 1]));
                *(ushort2*)&L.Kws[r][gq * 8 + 2 * p] = o;
            }
        }
        const unsigned short* Vg = Vb16 + ((size_t)b * LSEQ + t0) * DM + dg * 128;
#pragma unroll
        for (int l = 0; l < 4; ++l) {
            const int e = tid + l * 256;
            const int s = e >> 4, gg = e & 15;
            uint4 vr = *(const uint4*)(Vg + (size_t)s * DM + gg * 8);
            const unsigned short* vp = (const unsigned short*)&vr;
#pragma unroll
            for (int p = 0; p < 4; ++p) {
                ushort2 o;
                o.x = vp[2 * p]; o.y = vp[2 * p + 1];
                *(ushort2*)&L.Vs[s][gg * 8 + 2 * p] = o;
            }
        }
        __syncthreads();

        f32x4 sacc[2][2];
#pragma unroll
        for (int i = 0; i < 2; ++i)
#pragma unroll
            for (int j = 0; j < 2; ++j) sacc[i][j] = (f32x4)(0.f);
#pragma unroll
        for (int ks = 0; ks < 2; ++ks) {
            short8v qa[2], kb2[2];
#pragma unroll
            for (int mt = 0; mt < 2; ++mt)
                qa[mt] = *(const short8v*)&L.Qs[wr * 32 + mt * 16 + lr][ks * 32 + lk * 8];
#pragma unroll
            for (int nt = 0; nt < 2; ++nt)
                kb2[nt] = *(const short8v*)&L.Ks[wc * 32 + nt * 16 + lr][ks * 32 + lk * 8];
#pragma unroll
            for (int mt = 0; mt < 2; ++mt)
#pragma unroll
                for (int nt = 0; nt < 2; ++nt)
                    sacc[mt][nt] = __builtin_amdgcn_mfma_f32_16x16x32_bf16(
                        qa[mt], kb2[nt], sacc[mt][nt], 0, 0, 0);
        }

#pragma unroll
        for (int mt = 0; mt < 2; ++mt) {
#pragma unroll
            for (int j = 0; j < 4; ++j) {
                const int t = wr * 32 + mt * 16 + lk * 4 + j;
                const float ct = L.cps[t];
                float rowpart = 0.f;
#pragma unroll
                for (int nt = 0; nt < 2; ++nt) {
                    const int s = wc * 32 + nt * 16 + lr;
                    float v = sacc[mt][nt][j];
                    v = (s <= t) ? v * expf(ct - L.cps[s]) : 0.f;
                    rowpart += v;
                    L.As[t][s] = f2bf(v);
                }
                rowpart += __shfl_xor(rowpart, 1);
                rowpart += __shfl_xor(rowpart, 2);
                rowpart += __shfl_xor(rowpart, 4);
                rowpart += __shfl_xor(rowpart, 8);
                if (lr == 0) atomicAdd(&L.DIsh[t], rowpart);
            }
        }
        __syncthreads();

        if (dg == 0) {
            if (tid < 64) DI[(size_t)b * LSEQ + t0 + tid] = L.DIsh[tid];
            if (tid >= 64 && tid < 128) {
                const int m = tid - 64;
                float z = 0.f;
#pragma unroll
                for (int s = 0; s < 64; ++s) z += L.wks[s] * bf2f(L.Ks[s][m]);
                KZ[((size_t)b * NCHUNK + chunk) * MM + m] = z;
            }
        }

        f32x4 aO[2][4], aK[2][4];
#pragma unroll
        for (int i = 0; i < 2; ++i)
#pragma unroll
            for (int j = 0; j < 4; ++j) { aO[i][j] = (f32x4)(0.f); aK[i][j] = (f32x4)(0.f); }

#pragma unroll
        for (int ks = 0; ks < 2; ++ks) {
            short8v vf[4];
#pragma unroll
            for (int nt = 0; nt < 4; ++nt) {
                unsigned short* vp = (unsigned short*)&vf[nt];
                const int n = wc * 64 + nt * 16 + lr;
#pragma unroll
                for (int e = 0; e < 8; ++e)
                    vp[e] = L.Vs[ks * 32 + lk * 8 + e][n];
            }
            short8v af2[2], kf2[2];
#pragma unroll
            for (int mt = 0; mt < 2; ++mt) {
                const int row = wr * 32 + mt * 16 + lr;
                af2[mt] = *(const short8v*)&L.As[row][ks * 32 + lk * 8];
                unsigned short* kp = (unsigned short*)&kf2[mt];
#pragma unroll
                for (int e = 0; e < 8; ++e)
                    kp[e] = L.Kws[ks * 32 + lk * 8 + e][row];
            }
#pragma unroll
            for (int mt = 0; mt < 2; ++mt)
#pragma unroll
                for (int nt = 0; nt < 4; ++nt) {
                    aO[mt][nt] = __builtin_amdgcn_mfma_f32_16x16x32_bf16(
                        af2[mt], vf[nt], aO[mt][nt], 0, 0, 0);
                    aK[mt][nt] = __builtin_amdgcn_mfma_f32_16x16x32_bf16(
                        kf2[mt], vf[nt], aK[mt][nt], 0, 0, 0);
                }
        }

        float* OIb = OI + ((size_t)b * LSEQ + t0) * DM + dg * 128;
        float* KVb = KV + ((size_t)b * NCHUNK + chunk) * MM * DM + dg * 128;
#pragma unroll
        for (int mt = 0; mt < 2; ++mt)
#pragma unroll
            for (int nt = 0; nt < 4; ++nt) {
                const int col = wc * 64 + nt * 16 + lr;
#pragma unroll
                for (int j = 0; j < 4; ++j) {
                    const int row = wr * 32 + mt * 16 + lk * 4 + j;
                    OIb[(size_t)row * DM + col] = aO[mt][nt][j];
                    KVb[(size_t)row * DM + col] = aK[mt][nt][j];
                }
            }
    }
    grid.sync();

    // ================= phase 3: sequential state scan ========================
    {
        const int g = bid * 256 + tid;
        const int b = g >> 15;
        const int rem = g & 32767;
        const int m = rem >> 9;
        const int d = rem & 511;
        const size_t base = (((size_t)b * NCHUNK) * MM + m) * DM + d;
        const size_t cstride = (size_t)MM * DM;

        float v[NCHUNK];
#pragma unroll
        for (int i = 0; i < NCHUNK; ++i) v[i] = KV[base + (size_t)i * cstride];

        float s = 0.f, cprev = 0.f;
#pragma unroll
        for (int i = 0; i < NCHUNK; ++i) {
            const float ce = cpos(ld, i * CHK + CHK - 1);
            const float lam = expf(ce - cprev);
            cprev = ce;
            SSb[base + (size_t)i * cstride] = f2bf(s);
            s = lam * s + v[i];
        }
        if (d == 0) {
            float zs = 0.f;
            cprev = 0.f;
#pragma unroll
            for (int i = 0; i < NCHUNK; ++i) {
                const float ce = cpos(ld, i * CHK + CHK - 1);
                const float lam = expf(ce - cprev);
                cprev = ce;
                const int zi = (b * NCHUNK + i) * MM + m;
                ZS[zi] = zs;
                zs = lam * zs + KZ[zi];
            }
        }
    }
    grid.sync();

    // ================= phase 4: combine + DEN + RMS (row-split x2) ===========
    if (bid < 128) {
        const int chunk = bid & 31, half = (bid >> 5) & 1, b = bid >> 6;
        const int t0 = chunk * CHK;
        const int r0 = half * 32;
        const int w = wid;               // wave -> col block w*128
        auto& C = sm.c;

        // stage Q rows [t0+r0, +32)
        {
            const unsigned short* Qg = Qb16 + ((size_t)b * LSEQ + t0 + r0) * MM;
            const int e = tid;           // 256 uint4 = 2048 el
            const int r = e >> 3, g8 = e & 7;
            *(uint4*)&C.Qs[r][g8 * 8] = *(const uint4*)(Qg + (size_t)e * 8);
        }
        // stage S_prev (64x512 bf16)
        {
            const unsigned short* Sg = SSb + ((size_t)(b * NCHUNK + chunk) * MM) * DM;
#pragma unroll
            for (int l = 0; l < 16; ++l) {
                const int e = tid + l * 256;
                const int m = e >> 6, g8 = e & 63;
                uint4 v = *(const uint4*)(Sg + (size_t)m * DM + g8 * 8);
                const unsigned short* vp = (const unsigned short*)&v;
#pragma unroll
                for (int p = 0; p < 4; ++p) {
                    ushort2 o; o.x = vp[2 * p]; o.y = vp[2 * p + 1];
                    *(ushort2*)&C.Ssh[m][g8 * 8 + 2 * p] = o;
                }
            }
        }
        C.wsh[tid] = norm_w[tid];
        C.wsh[tid + 256] = norm_w[tid + 256];
        if (tid < 32) {
            const float cprev = (chunk > 0) ? cpos(ld, t0 - 1) : 0.f;
            C.gv[tid] = expf(cpos(ld, t0 + r0 + tid) - cprev);
            C.xsq[tid] = 0.f;
        }
        __syncthreads();

        if (tid < 32) {
            const float* zp = ZS + ((size_t)b * NCHUNK + chunk) * MM;
            float a = 0.f;
#pragma unroll
            for (int m = 0; m < MM; ++m) a += bf2f(C.Qs[tid][m]) * zp[m];
            C.invden[tid] = 1.0f /
                (C.gv[tid] * a + DI[(size_t)b * LSEQ + t0 + r0 + tid] + 1e-6f);
        }

        // O_inter = Q(32x64) @ S_prev(64x512): wave w covers cols w*128..+128
        f32x4 acc[2][8];
#pragma unroll
        for (int i = 0; i < 2; ++i)
#pragma unroll
            for (int j = 0; j < 8; ++j) acc[i][j] = (f32x4)(0.f);

#pragma unroll
        for (int ks = 0; ks < 2; ++ks) {
            short8v vf[8];
#pragma unroll
            for (int nt = 0; nt < 8; ++nt) {
                unsigned short* vp = (unsigned short*)&vf[nt];
                const int col = w * 128 + nt * 16 + lr;
#pragma unroll
                for (int e = 0; e < 8; ++e)
                    vp[e] = C.Ssh[ks * 32 + lk * 8 + e][col];
            }
            short8v af[2];
#pragma unroll
            for (int mt = 0; mt < 2; ++mt)
                af[mt] = *(const short8v*)&C.Qs[mt * 16 + lr][ks * 32 + lk * 8];
#pragma unroll
            for (int mt = 0; mt < 2; ++mt)
#pragma unroll
                for (int nt = 0; nt < 8; ++nt)
                    acc[mt][nt] = __builtin_amdgcn_mfma_f32_16x16x32_bf16(
                        af[mt], vf[nt], acc[mt][nt], 0, 0, 0);
        }
        __syncthreads();   // invden visible

        const float* OIb = OI + ((size_t)b * LSEQ + t0 + r0) * DM;
#pragma unroll
        for (int mt = 0; mt < 2; ++mt) {
#pragma unroll
            for (int j = 0; j < 4; ++j) {
                const int row = mt * 16 + lk * 4 + j;
                const float g = C.gv[row];
                const float inv = C.invden[row];
                float part = 0.f;
#pragma unroll
                for (int nt = 0; nt < 8; ++nt) {
                    const int col = w * 128 + nt * 16 + lr;
                    float v = g * acc[mt][nt][j] + OIb[(size_t)row * DM + col];
                    float xx = v * inv;
                    acc[mt][nt][j] = xx;
                    part += xx * xx;
                }
                part += __shfl_xor(part, 1);
                part += __shfl_xor(part, 2);
                part += __shfl_xor(part, 4);
                part += __shfl_xor(part, 8);
                if (lr == 0) atomicAdd(&C.xsq[row], part);
            }
        }
        __syncthreads();
        if (tid < 32)
            C.rinv[tid] = 1.0f / sqrtf(C.xsq[tid] * (1.0f / (float)DM) + 1e-6f);
        __syncthreads();

        unsigned short* NRMc = NRMb + ((size_t)b * LSEQ + t0 + r0) * DM;
#pragma unroll
        for (int mt = 0; mt < 2; ++mt)
#pragma unroll
            for (int j = 0; j < 4; ++j) {
                const int row = mt * 16 + lk * 4 + j;
                const float r = C.rinv[row];
#pragma unroll
                for (int nt = 0; nt < 8; ++nt) {
                    const int col = w * 128 + nt * 16 + lr;
                    NRMc[(size_t)row * DM + col] = f2bf(acc[mt][nt][j] * r * C.wsh[col]);
                }
            }
    }
    grid.sync();

    // ================= phase 5: output projection (64x128 tiles) =============
    {
        const int brow = (bid & 63) * 64;
        const int bcol = (bid >> 6) * 128;
        const int wr = wid >> 1, wc = wid & 1;

        f32x4 acc[2][4];
#pragma unroll
        for (int i = 0; i < 2; ++i)
#pragma unroll
            for (int j = 0; j < 4; ++j) acc[i][j] = (f32x4)(0.f);

        for (int k0 = 0; k0 < DM; k0 += 32) {
            {
                const int r = tid >> 2, kg = tid & 3;   // 2048 el A-tile
                *(uint4*)&sm.g.A[r][kg * 8] =
                    *(const uint4*)&NRMb[(size_t)(brow + r) * DM + k0 + kg * 8];
            }
#pragma unroll
            for (int i = 0; i < 2; ++i) {
                int c = tid * 2 + i;
                int r = c >> 2, kg = c & 3;
                *(uint4*)&sm.g.B[r][kg * 8] =
                    *(const uint4*)&Wob16[(size_t)(bcol + r) * DM + k0 + kg * 8];
            }
            __syncthreads();
            short8v af[2], bf[4];
#pragma unroll
            for (int mt = 0; mt < 2; ++mt)
                af[mt] = *(const short8v*)&sm.g.A[wr * 32 + mt * 16 + lr][lk * 8];
#pragma unroll
            for (int nt = 0; nt < 4; ++nt)
                bf[nt] = *(const short8v*)&sm.g.B[wc * 64 + nt * 16 + lr][lk * 8];
#pragma unroll
            for (int mt = 0; mt < 2; ++mt)
#pragma unroll
                for (int nt = 0; nt < 4; ++nt)
                    acc[mt][nt] = __builtin_amdgcn_mfma_f32_16x16x32_bf16(
                        af[mt], bf[nt], acc[mt][nt], 0, 0, 0);
            __syncthreads();
        }

#pragma unroll
        for (int mt = 0; mt < 2; ++mt)
#pragma unroll
            for (int nt = 0; nt < 4; ++nt) {
                const int row0 = brow + wr * 32 + mt * 16 + lk * 4;
                const int col = bcol + wc * 64 + nt * 16 + lr;
#pragma unroll
                for (int j = 0; j < 4; ++j)
                    out[(size_t)(row0 + j) * DM + col] = acc[mt][nt][j];
            }
    }
}

extern "C" void kernel_launch(void* const* d_in, const int* in_sizes, int n_in,
                              void* d_out, int out_size, void* d_ws, size_t ws_size,
                              hipStream_t stream) {
    const float* x      = (const float*)d_in[0];
    const float* W_q    = (const float*)d_in[1];
    const float* W_k    = (const float*)d_in[2];
    const float* W_v    = (const float*)d_in[3];
    const float* W_o    = (const float*)d_in[4];
    const float* logit  = (const float*)d_in[5];
    const float* norm_w = (const float*)d_in[6];
    float* out = (float*)d_out;
    float* wsf = (float*)d_ws;

    void* args[9];
    args[0] = (void*)&x;
    args[1] = (void*)&W_q;
    args[2] = (void*)&W_k;
    args[3] = (void*)&W_v;
    args[4] = (void*)&W_o;
    args[5] = (void*)&logit;
    args[6] = (void*)&norm_w;
    args[7] = (void*)&out;
    args[8] = (void*)&wsf;

    hipLaunchCooperativeKernel(reinterpret_cast<void*>(mega),
                               dim3(256), dim3(256), args, 0, stream);
}

// Round 6
// 64.363 us; speedup vs baseline: 3.1785x; 3.1785x over previous
//
#include <hip/hip_runtime.h>
#include <math.h>

#define NB 2
#define LSEQ 2048
#define DM 512
#define MM 64
#define CHK 64
#define NCHUNK 32

typedef __attribute__((ext_vector_type(8))) short short8v;
typedef __attribute__((ext_vector_type(4))) float f32x4;

__device__ __forceinline__ float get_ld(const float* __restrict__ logit) {
    float lg = *logit;
    float dec = 1.0f / (1.0f + expf(-lg));
    dec = fmaxf(dec, 1e-6f);
    return logf(dec);
}
__device__ __forceinline__ float cpos(float ld, int t) {
    return fminf(fmaxf(ld * (float)t, -20.0f), 20.0f);
}
__device__ __forceinline__ float phi_fn(float v) {
    return v > 0.0f ? v + 1.0f : expf(v);
}
__device__ __forceinline__ unsigned short f2bf(float f) {
    unsigned int u = __float_as_uint(f);
    u += 0x7FFFu + ((u >> 16) & 1u);   // RNE
    return (unsigned short)(u >> 16);
}
__device__ __forceinline__ float bf2f(unsigned short h) {
    unsigned int u = ((unsigned int)h) << 16;
    return __uint_as_float(u);
}
// load 8 f32, convert to 8 bf16 packed in a uint4
__device__ __forceinline__ uint4 cvt8(const float* __restrict__ p) {
    float4 a = *(const float4*)p;
    float4 b = *(const float4*)(p + 4);
    union { unsigned short u[8]; uint4 v; } r;
    r.u[0] = f2bf(a.x); r.u[1] = f2bf(a.y); r.u[2] = f2bf(a.z); r.u[3] = f2bf(a.w);
    r.u[4] = f2bf(b.x); r.u[5] = f2bf(b.y); r.u[6] = f2bf(b.z); r.u[7] = f2bf(b.w);
    return r.v;
}

// ---- fused QKV projection (cvt-on-the-fly) + W_o cvt slice ----
// grid (64, 6): y=0 QK (cols = Wq|Wk), y=1..4 V col slices, y=5 W_o cvt
__global__ __launch_bounds__(256) void gemm_proj(
    const float* __restrict__ x, const float* __restrict__ W_q,
    const float* __restrict__ W_k, const float* __restrict__ W_v,
    const float* __restrict__ W_o,
    unsigned short* __restrict__ Qh, unsigned short* __restrict__ Kh,
    unsigned short* __restrict__ Vh, unsigned short* __restrict__ Wob)
{
    const int cb = blockIdx.y;
    const int tid = threadIdx.x;
    if (cb == 5) {  // W_o -> bf16 (64 blocks x 4 float4)
        const int stride = 64 * 256;
#pragma unroll
        for (int it = 0; it < 4; ++it) {
            int i = blockIdx.x * 256 + tid + it * stride;
            float4 v = ((const float4*)W_o)[i];
            ushort4 o;
            o.x = f2bf(v.x); o.y = f2bf(v.y); o.z = f2bf(v.z); o.w = f2bf(v.w);
            ((ushort4*)Wob)[i] = o;
        }
        return;
    }

    __shared__ unsigned short As[64][40];
    __shared__ unsigned short Bs[128][40];
    const int brow = blockIdx.x * 64;
    const int lane = tid & 63, wid = tid >> 6;
    const int wr = wid >> 1, wc = wid & 1;
    const int lr = lane & 15, lk = lane >> 4;

    f32x4 acc[2][4];
#pragma unroll
    for (int i = 0; i < 2; ++i)
#pragma unroll
        for (int j = 0; j < 4; ++j) acc[i][j] = (f32x4)(0.f);

    for (int k0 = 0; k0 < DM; k0 += 32) {
        {   // A tile: 64x32 f32 -> bf16
            const int r = tid >> 2, kg = tid & 3;
            *(uint4*)&As[r][kg * 8] = cvt8(&x[(size_t)(brow + r) * DM + k0 + kg * 8]);
        }
#pragma unroll
        for (int i = 0; i < 2; ++i) {   // B tile: 128x32
            int c = tid * 2 + i;
            int r = c >> 2, kg = c & 3;
            const float* wsrc;
            if (cb == 0)
                wsrc = (r < 64) ? &W_q[(size_t)r * DM + k0 + kg * 8]
                                : &W_k[(size_t)(r - 64) * DM + k0 + kg * 8];
            else
                wsrc = &W_v[(size_t)((cb - 1) * 128 + r) * DM + k0 + kg * 8];
            *(uint4*)&Bs[r][kg * 8] = cvt8(wsrc);
        }
        __syncthreads();
        short8v af[2], bf[4];
#pragma unroll
        for (int mt = 0; mt < 2; ++mt)
            af[mt] = *(const short8v*)&As[wr * 32 + mt * 16 + lr][lk * 8];
#pragma unroll
        for (int nt = 0; nt < 4; ++nt)
            bf[nt] = *(const short8v*)&Bs[wc * 64 + nt * 16 + lr][lk * 8];
#pragma unroll
        for (int mt = 0; mt < 2; ++mt)
#pragma unroll
            for (int nt = 0; nt < 4; ++nt)
                acc[mt][nt] = __builtin_amdgcn_mfma_f32_16x16x32_bf16(
                    af[mt], bf[nt], acc[mt][nt], 0, 0, 0);
        __syncthreads();
    }

#pragma unroll
    for (int mt = 0; mt < 2; ++mt)
#pragma unroll
        for (int nt = 0; nt < 4; ++nt) {
            const int col = wc * 64 + nt * 16 + lr;
#pragma unroll
            for (int j = 0; j < 4; ++j) {
                const int row = brow + wr * 32 + mt * 16 + lk * 4 + j;
                float v = acc[mt][nt][j];
                if (cb == 0) {
                    v = phi_fn(v);
                    if (col < 64)
                        Qh[(size_t)row * MM + col] = f2bf(v * 0.125f);
                    else
                        Kh[(size_t)row * MM + (col - 64)] = f2bf(v);
                } else {
                    Vh[(size_t)row * DM + (cb - 1) * 128 + col] = f2bf(v);
                }
            }
        }
}

// ---- intra-chunk attention + summaries, all MFMA ----
__global__ __launch_bounds__(256) void chunk_local_mfma(
    const unsigned short* __restrict__ Qb, const unsigned short* __restrict__ Kb,
    const unsigned short* __restrict__ Vb, const float* __restrict__ logit,
    float* __restrict__ OI, float* __restrict__ DI,
    float* __restrict__ KV, float* __restrict__ KZ)
{
    const int chunk = blockIdx.x, dg = blockIdx.y, b = blockIdx.z;
    const int tid = threadIdx.x;
    const int lane = tid & 63, wid = tid >> 6;
    const int wr = wid >> 1, wc = wid & 1;
    const int lr = lane & 15, lk = lane >> 4;
    const int t0 = chunk * CHK;
    const float ld = get_ld(logit);

    __shared__ unsigned short Qs[64][72];
    __shared__ unsigned short Ks[64][72];
    __shared__ unsigned short As[64][72];
    __shared__ unsigned short Kws[64][66];
    __shared__ unsigned short Vs[64][134];
    __shared__ float wks[64];
    __shared__ float cps[64];
    __shared__ float DIsh[64];

    if (tid < 64) {
        const float c = cpos(ld, t0 + tid);
        cps[tid] = c;
        wks[tid] = expf(cpos(ld, t0 + CHK - 1) - c);
        DIsh[tid] = 0.f;
    }
    __syncthreads();

    const unsigned short* Qg = Qb + ((size_t)b * LSEQ + t0) * MM;
    const unsigned short* Kg = Kb + ((size_t)b * LSEQ + t0) * MM;
#pragma unroll
    for (int l = 0; l < 2; ++l) {
        const int e = tid + l * 256;
        const int r = e >> 3, gq = e & 7;
        *(uint4*)&Qs[r][gq * 8] = *(const uint4*)(Qg + (size_t)e * 8);
        uint4 kraw = *(const uint4*)(Kg + (size_t)e * 8);
        *(uint4*)&Ks[r][gq * 8] = kraw;
        const float w = wks[r];
        const unsigned short* kp = (const unsigned short*)&kraw;
#pragma unroll
        for (int p = 0; p < 4; ++p) {
            ushort2 o;
            o.x = f2bf(w * bf2f(kp[2 * p]));
            o.y = f2bf(w * bf2f(kp[2 * p + 1]));
            *(ushort2*)&Kws[r][gq * 8 + 2 * p] = o;
        }
    }
    const unsigned short* Vg = Vb + ((size_t)b * LSEQ + t0) * DM + dg * 128;
#pragma unroll
    for (int l = 0; l < 4; ++l) {
        const int e = tid + l * 256;
        const int s = e >> 4, gg = e & 15;
        uint4 vr = *(const uint4*)(Vg + (size_t)s * DM + gg * 8);
        const unsigned short* vp = (const unsigned short*)&vr;
#pragma unroll
        for (int p = 0; p < 4; ++p) {
            ushort2 o;
            o.x = vp[2 * p]; o.y = vp[2 * p + 1];
            *(ushort2*)&Vs[s][gg * 8 + 2 * p] = o;
        }
    }
    __syncthreads();

    f32x4 sacc[2][2];
#pragma unroll
    for (int i = 0; i < 2; ++i)
#pragma unroll
        for (int j = 0; j < 2; ++j) sacc[i][j] = (f32x4)(0.f);
#pragma unroll
    for (int ks = 0; ks < 2; ++ks) {
        short8v qa[2], kb2[2];
#pragma unroll
        for (int mt = 0; mt < 2; ++mt)
            qa[mt] = *(const short8v*)&Qs[wr * 32 + mt * 16 + lr][ks * 32 + lk * 8];
#pragma unroll
        for (int nt = 0; nt < 2; ++nt)
            kb2[nt] = *(const short8v*)&Ks[wc * 32 + nt * 16 + lr][ks * 32 + lk * 8];
#pragma unroll
        for (int mt = 0; mt < 2; ++mt)
#pragma unroll
            for (int nt = 0; nt < 2; ++nt)
                sacc[mt][nt] = __builtin_amdgcn_mfma_f32_16x16x32_bf16(
                    qa[mt], kb2[nt], sacc[mt][nt], 0, 0, 0);
    }

#pragma unroll
    for (int mt = 0; mt < 2; ++mt) {
#pragma unroll
        for (int j = 0; j < 4; ++j) {
            const int t = wr * 32 + mt * 16 + lk * 4 + j;
            const float ct = cps[t];
            float rowpart = 0.f;
#pragma unroll
            for (int nt = 0; nt < 2; ++nt) {
                const int s = wc * 32 + nt * 16 + lr;
                float v = sacc[mt][nt][j];
                v = (s <= t) ? v * expf(ct - cps[s]) : 0.f;
                rowpart += v;
                As[t][s] = f2bf(v);
            }
            rowpart += __shfl_xor(rowpart, 1);
            rowpart += __shfl_xor(rowpart, 2);
            rowpart += __shfl_xor(rowpart, 4);
            rowpart += __shfl_xor(rowpart, 8);
            if (lr == 0) atomicAdd(&DIsh[t], rowpart);
        }
    }
    __syncthreads();

    if (dg == 0) {
        if (tid < 64) DI[(size_t)b * LSEQ + t0 + tid] = DIsh[tid];
        if (tid >= 64 && tid < 128) {
            const int m = tid - 64;
            float z = 0.f;
#pragma unroll
            for (int s = 0; s < 64; ++s) z += wks[s] * bf2f(Ks[s][m]);
            KZ[((size_t)b * NCHUNK + chunk) * MM + m] = z;
        }
    }

    f32x4 aO[2][4], aK[2][4];
#pragma unroll
    for (int i = 0; i < 2; ++i)
#pragma unroll
        for (int j = 0; j < 4; ++j) { aO[i][j] = (f32x4)(0.f); aK[i][j] = (f32x4)(0.f); }

#pragma unroll
    for (int ks = 0; ks < 2; ++ks) {
        short8v vf[4];
#pragma unroll
        for (int nt = 0; nt < 4; ++nt) {
            unsigned short* vp = (unsigned short*)&vf[nt];
            const int n = wc * 64 + nt * 16 + lr;
#pragma unroll
            for (int e = 0; e < 8; ++e)
                vp[e] = Vs[ks * 32 + lk * 8 + e][n];
        }
        short8v af2[2], kf2[2];
#pragma unroll
        for (int mt = 0; mt < 2; ++mt) {
            const int row = wr * 32 + mt * 16 + lr;
            af2[mt] = *(const short8v*)&As[row][ks * 32 + lk * 8];
            unsigned short* kp = (unsigned short*)&kf2[mt];
#pragma unroll
            for (int e = 0; e < 8; ++e)
                kp[e] = Kws[ks * 32 + lk * 8 + e][row];
        }
#pragma unroll
        for (int mt = 0; mt < 2; ++mt)
#pragma unroll
            for (int nt = 0; nt < 4; ++nt) {
                aO[mt][nt] = __builtin_amdgcn_mfma_f32_16x16x32_bf16(
                    af2[mt], vf[nt], aO[mt][nt], 0, 0, 0);
                aK[mt][nt] = __builtin_amdgcn_mfma_f32_16x16x32_bf16(
                    kf2[mt], vf[nt], aK[mt][nt], 0, 0, 0);
            }
    }

    float* OIb = OI + ((size_t)b * LSEQ + t0) * DM + dg * 128;
    float* KVb = KV + ((size_t)b * NCHUNK + chunk) * MM * DM + dg * 128;
#pragma unroll
    for (int mt = 0; mt < 2; ++mt)
#pragma unroll
        for (int nt = 0; nt < 4; ++nt) {
            const int col = wc * 64 + nt * 16 + lr;
#pragma unroll
            for (int j = 0; j < 4; ++j) {
                const int row = wr * 32 + mt * 16 + lk * 4 + j;
                OIb[(size_t)row * DM + col] = aO[mt][nt][j];
                KVb[(size_t)row * DM + col] = aK[mt][nt][j];
            }
        }
}

// ---- sequential scan over chunks; S_prev emitted bf16 ----
__global__ __launch_bounds__(256) void state_scan(
    const float* __restrict__ KV, const float* __restrict__ KZ,
    const float* __restrict__ logit,
    unsigned short* __restrict__ SS, float* __restrict__ ZS)
{
    const int g = blockIdx.x * 256 + threadIdx.x;
    const int b = g >> 15;
    const int rem = g & 32767;
    const int m = rem >> 9;
    const int d = rem & 511;
    const float ld = get_ld(logit);
    const size_t base = (((size_t)b * NCHUNK) * MM + m) * DM + d;
    const size_t cstride = (size_t)MM * DM;

    float v[NCHUNK];
#pragma unroll
    for (int i = 0; i < NCHUNK; ++i) v[i] = KV[base + (size_t)i * cstride];

    float s = 0.f, cprev = 0.f;
#pragma unroll
    for (int i = 0; i < NCHUNK; ++i) {
        const float ce = cpos(ld, i * CHK + CHK - 1);
        const float lam = expf(ce - cprev);
        cprev = ce;
        SS[base + (size_t)i * cstride] = f2bf(s);
        s = lam * s + v[i];
    }
    if (d == 0) {
        float zs = 0.f;
        cprev = 0.f;
#pragma unroll
        for (int i = 0; i < NCHUNK; ++i) {
            const float ce = cpos(ld, i * CHK + CHK - 1);
            const float lam = expf(ce - cprev);
            cprev = ce;
            const int zi = (b * NCHUNK + i) * MM + m;
            ZS[zi] = zs;
            zs = lam * zs + KZ[zi];
        }
    }
}

// ---- fused inter-chunk combine + DEN + RMS norm -> bf16 (row-split x2) ----
// grid (NCHUNK, 2, NB)
__global__ __launch_bounds__(256) void combine_rms(
    const unsigned short* __restrict__ Qb, const unsigned short* __restrict__ SSb,
    const float* __restrict__ ZS, const float* __restrict__ OI,
    const float* __restrict__ DI, const float* __restrict__ logit,
    const float* __restrict__ norm_w, unsigned short* __restrict__ NRM)
{
    const int chunk = blockIdx.x, half = blockIdx.y, b = blockIdx.z;
    const int tid = threadIdx.x;
    const int lane = tid & 63, w = tid >> 6;   // wave -> col block w*128
    const int lr = lane & 15, lk = lane >> 4;
    const int t0 = chunk * CHK;
    const int r0 = half * 32;
    const float ld = get_ld(logit);

    __shared__ unsigned short Qs[32][72];
    __shared__ unsigned short Ssh[64][514];   // strided u16 reads conflict-free
    __shared__ float wsh[512];
    __shared__ float gv[32], invden[32], xsq[32], rinv[32];

    // stage Q rows [t0+r0, +32)
    {
        const unsigned short* Qg = Qb + ((size_t)b * LSEQ + t0 + r0) * MM;
        const int r = tid >> 3, g8 = tid & 7;
        *(uint4*)&Qs[r][g8 * 8] = *(const uint4*)(Qg + (size_t)tid * 8);
    }
    // stage S_prev (64x512 bf16)
    {
        const unsigned short* Sg = SSb + ((size_t)(b * NCHUNK + chunk) * MM) * DM;
#pragma unroll
        for (int l = 0; l < 16; ++l) {
            const int e = tid + l * 256;
            const int m = e >> 6, g8 = e & 63;
            uint4 v = *(const uint4*)(Sg + (size_t)m * DM + g8 * 8);
            const unsigned short* vp = (const unsigned short*)&v;
#pragma unroll
            for (int p = 0; p < 4; ++p) {
                ushort2 o; o.x = vp[2 * p]; o.y = vp[2 * p + 1];
                *(ushort2*)&Ssh[m][g8 * 8 + 2 * p] = o;
            }
        }
    }
    wsh[tid] = norm_w[tid];
    wsh[tid + 256] = norm_w[tid + 256];
    if (tid < 32) {
        const float cprev = (chunk > 0) ? cpos(ld, t0 - 1) : 0.f;
        gv[tid] = expf(cpos(ld, t0 + r0 + tid) - cprev);
        xsq[tid] = 0.f;
    }
    __syncthreads();

    if (tid < 32) {
        const float* zp = ZS + ((size_t)b * NCHUNK + chunk) * MM;
        float a = 0.f;
#pragma unroll
        for (int m = 0; m < MM; ++m) a += bf2f(Qs[tid][m]) * zp[m];
        invden[tid] = 1.0f /
            (gv[tid] * a + DI[(size_t)b * LSEQ + t0 + r0 + tid] + 1e-6f);
    }

    // O_inter = Q(32x64) @ S_prev(64x512): wave w covers cols w*128..+128
    f32x4 acc[2][8];
#pragma unroll
    for (int i = 0; i < 2; ++i)
#pragma unroll
        for (int j = 0; j < 8; ++j) acc[i][j] = (f32x4)(0.f);

#pragma unroll
    for (int ks = 0; ks < 2; ++ks) {
        short8v vf[8];
#pragma unroll
        for (int nt = 0; nt < 8; ++nt) {
            unsigned short* vp = (unsigned short*)&vf[nt];
            const int col = w * 128 + nt * 16 + lr;
#pragma unroll
            for (int e = 0; e < 8; ++e)
                vp[e] = Ssh[ks * 32 + lk * 8 + e][col];
        }
        short8v af[2];
#pragma unroll
        for (int mt = 0; mt < 2; ++mt)
            af[mt] = *(const short8v*)&Qs[mt * 16 + lr][ks * 32 + lk * 8];
#pragma unroll
        for (int mt = 0; mt < 2; ++mt)
#pragma unroll
            for (int nt = 0; nt < 8; ++nt)
                acc[mt][nt] = __builtin_amdgcn_mfma_f32_16x16x32_bf16(
                    af[mt], vf[nt], acc[mt][nt], 0, 0, 0);
    }
    __syncthreads();   // invden visible

    const float* OIb = OI + ((size_t)b * LSEQ + t0 + r0) * DM;
#pragma unroll
    for (int mt = 0; mt < 2; ++mt) {
#pragma unroll
        for (int j = 0; j < 4; ++j) {
            const int row = mt * 16 + lk * 4 + j;
            const float g = gv[row];
            const float inv = invden[row];
            float part = 0.f;
#pragma unroll
            for (int nt = 0; nt < 8; ++nt) {
                const int col = w * 128 + nt * 16 + lr;
                float v = g * acc[mt][nt][j] + OIb[(size_t)row * DM + col];
                float xx = v * inv;
                acc[mt][nt][j] = xx;
                part += xx * xx;
            }
            part += __shfl_xor(part, 1);
            part += __shfl_xor(part, 2);
            part += __shfl_xor(part, 4);
            part += __shfl_xor(part, 8);
            if (lr == 0) atomicAdd(&xsq[row], part);
        }
    }
    __syncthreads();
    if (tid < 32)
        rinv[tid] = 1.0f / sqrtf(xsq[tid] * (1.0f / (float)DM) + 1e-6f);
    __syncthreads();

    unsigned short* NRMc = NRM + ((size_t)b * LSEQ + t0 + r0) * DM;
#pragma unroll
    for (int mt = 0; mt < 2; ++mt)
#pragma unroll
        for (int j = 0; j < 4; ++j) {
            const int row = mt * 16 + lk * 4 + j;
            const float r = rinv[row];
#pragma unroll
            for (int nt = 0; nt < 8; ++nt) {
                const int col = w * 128 + nt * 16 + lr;
                NRMc[(size_t)row * DM + col] = f2bf(acc[mt][nt][j] * r * wsh[col]);
            }
        }
}

// ---- output GEMM: 64x128 tiles, grid (64,4) ----
__global__ __launch_bounds__(256) void gemm_out(
    const unsigned short* __restrict__ Xb, const unsigned short* __restrict__ Wb,
    float* __restrict__ C)
{
    __shared__ unsigned short As[64][40];
    __shared__ unsigned short Bs[128][40];
    const int brow = blockIdx.x * 64;
    const int bcol = blockIdx.y * 128;
    const int tid = threadIdx.x;
    const int lane = tid & 63, wid = tid >> 6;
    const int wr = wid >> 1, wc = wid & 1;
    const int lr = lane & 15, lk = lane >> 4;

    f32x4 acc[2][4];
#pragma unroll
    for (int i = 0; i < 2; ++i)
#pragma unroll
        for (int j = 0; j < 4; ++j) acc[i][j] = (f32x4)(0.f);

    for (int k0 = 0; k0 < DM; k0 += 32) {
        {
            const int r = tid >> 2, kg = tid & 3;
            *(uint4*)&As[r][kg * 8] =
                *(const uint4*)&Xb[(size_t)(brow + r) * DM + k0 + kg * 8];
        }
#pragma unroll
        for (int i = 0; i < 2; ++i) {
            int c = tid * 2 + i;
            int r = c >> 2, kg = c & 3;
            *(uint4*)&Bs[r][kg * 8] =
                *(const uint4*)&Wb[(size_t)(bcol + r) * DM + k0 + kg * 8];
        }
        __syncthreads();
        short8v af[2], bf[4];
#pragma unroll
        for (int mt = 0; mt < 2; ++mt)
            af[mt] = *(const short8v*)&As[wr * 32 + mt * 16 + lr][lk * 8];
#pragma unroll
        for (int nt = 0; nt < 4; ++nt)
            bf[nt] = *(const short8v*)&Bs[wc * 64 + nt * 16 + lr][lk * 8];
#pragma unroll
        for (int mt = 0; mt < 2; ++mt)
#pragma unroll
            for (int nt = 0; nt < 4; ++nt)
                acc[mt][nt] = __builtin_amdgcn_mfma_f32_16x16x32_bf16(
                    af[mt], bf[nt], acc[mt][nt], 0, 0, 0);
        __syncthreads();
    }

#pragma unroll
    for (int mt = 0; mt < 2; ++mt)
#pragma unroll
        for (int nt = 0; nt < 4; ++nt) {
            const int row0 = brow + wr * 32 + mt * 16 + lk * 4;
            const int col = bcol + wc * 64 + nt * 16 + lr;
#pragma unroll
            for (int j = 0; j < 4; ++j)
                C[(size_t)(row0 + j) * DM + col] = acc[mt][nt][j];
        }
}

extern "C" void kernel_launch(void* const* d_in, const int* in_sizes, int n_in,
                              void* d_out, int out_size, void* d_ws, size_t ws_size,
                              hipStream_t stream) {
    const float* x      = (const float*)d_in[0];
    const float* W_q    = (const float*)d_in[1];
    const float* W_k    = (const float*)d_in[2];
    const float* W_v    = (const float*)d_in[3];
    const float* W_o    = (const float*)d_in[4];
    const float* logit  = (const float*)d_in[5];
    const float* norm_w = (const float*)d_in[6];
    float* out = (float*)d_out;

    const size_t BLM = (size_t)NB * LSEQ * MM;          // 262144
    const size_t BLD = (size_t)NB * LSEQ * DM;          // 2097152
    const size_t BL  = (size_t)NB * LSEQ;               // 4096
    const size_t BNCMD = (size_t)NB * NCHUNK * MM * DM; // 2097152
    const size_t BNCM  = (size_t)NB * NCHUNK * MM;      // 4096
    const size_t WSZ = (size_t)DM * DM;                 // 262144

    float* ws = (float*)d_ws;
    float* OIp  = ws;
    float* DIp  = OIp + BLD;
    float* KVp  = DIp + BL;
    float* KZp  = KVp + BNCMD;
    float* ZSp  = KZp + BNCM;
    unsigned short* Wob16 = (unsigned short*)(ZSp + BNCM);
    unsigned short* Qb16 = Wob16 + WSZ;
    unsigned short* Kb16 = Qb16 + BLM;
    unsigned short* Vb16 = Kb16 + BLM;
    unsigned short* SSb  = Vb16 + BLD;
    unsigned short* NRMb = SSb + BNCMD;

    // 1. fused QKV projection (+ W_o cvt)
    gemm_proj<<<dim3(64, 6), 256, 0, stream>>>(x, W_q, W_k, W_v, W_o,
                                               Qb16, Kb16, Vb16, Wob16);
    // 2. intra-chunk attention + summaries
    chunk_local_mfma<<<dim3(NCHUNK, 4, NB), 256, 0, stream>>>(
        Qb16, Kb16, Vb16, logit, OIp, DIp, KVp, KZp);
    // 3. sequential state scan
    state_scan<<<dim3(256), 256, 0, stream>>>(KVp, KZp, logit, SSb, ZSp);
    // 4. combine + DEN + RMS -> bf16 (row-split)
    combine_rms<<<dim3(NCHUNK, 2, NB), 256, 0, stream>>>(
        Qb16, SSb, ZSp, OIp, DIp, logit, norm_w, NRMb);
    // 5. output projection
    gemm_out<<<dim3(64, 4), 256, 0, stream>>>(NRMb, Wob16, out);
}